// Round 5
// baseline (183.596 us; speedup 1.0000x reference)
//
#include <hip/hip_runtime.h>

#define B_ 4
#define C_ 64
#define H_ 256
#define W_ 256
#define KK 9

typedef __attribute__((ext_vector_type(8))) short short8;
typedef __attribute__((ext_vector_type(4))) float float4_;

static __device__ __forceinline__ unsigned short f2bf(float f) {
    unsigned int u = __builtin_bit_cast(unsigned int, f);
    unsigned int r = (u + 0x7fffu + ((u >> 16) & 1u)) >> 16;  // RNE
    return (unsigned short)r;
}
static __device__ __forceinline__ float bf2f(short s) {
    return __builtin_bit_cast(float, (unsigned int)((unsigned short)s) << 16);
}

// ---------------- Kernel A: NCHW fp32 -> NHWC bf16 (LDS transpose) ----------------
__global__ __launch_bounds__(256) void nchw2nhwc(
    const float* __restrict__ x, unsigned short* __restrict__ xh)
{
    __shared__ unsigned short t[256 * 66];
    int row = blockIdx.x;                   // b*256 + h
    int b = row >> 8;
    const float* src = x + ((size_t)b * 64) * 65536 + (size_t)(row & 255) * 256;
    int tid = threadIdx.x;

    #pragma unroll 4
    for (int c = 0; c < 64; ++c)
        t[tid * 66 + c] = f2bf(src[(size_t)c * 65536 + tid]);
    __syncthreads();

    unsigned short* dst = xh + (size_t)row * 256 * 64;
    #pragma unroll
    for (int it = 0; it < 8; ++it) {
        int idx = it * 256 + tid;
        int pix = idx >> 3, g = idx & 7;
        short8 v = *(const short8*)(&t[pix * 66 + g * 8]);
        *(short8*)(dst + (size_t)pix * 64 + g * 8) = v;
    }
}

// ---------------- Kernel B: merged weight transforms ----------------
// wb  [25 tap][8 q][16 n][8 e] bf16 from w_sharp [9][64][5][5]
// wb3 [ 9 tap][8 q][16 n][8 e] bf16 from w_r1   [9][64][3][3]
__global__ __launch_bounds__(256) void wprep_all(
    const float* __restrict__ w5, const float* __restrict__ w3,
    unsigned short* __restrict__ wb, unsigned short* __restrict__ wb3)
{
    int i = blockIdx.x * 256 + threadIdx.x;   // 25600 + 9216 = 34816
    if (i < 25600) {
        int tap = i >> 10;
        int q = (i >> 7) & 7;
        int n = (i >> 3) & 15;
        int e = i & 7;
        int c = q * 8 + e;
        int di = tap / 5, dj = tap % 5;
        float v = (n < KK) ? w5[((n * C_ + c) * 5 + di) * 5 + dj] : 0.f;
        wb[i] = f2bf(v);
    } else if (i < 34816) {
        int k = i - 25600;
        int tap = k >> 10;
        int q = (k >> 7) & 7;
        int n = (k >> 3) & 15;
        int e = k & 7;
        int c = q * 8 + e;
        int di = tap / 3, dj = tap % 3;
        float v = (n < KK) ? w3[((n * C_ + c) * 3 + di) * 3 + dj] : 0.f;
        wb3[k] = f2bf(v);
    }
}

// ---------------- Kernel C: conv5 + tanh via bf16 MFMA (att out bf16) ----------------
#define PADC 66   // stride 33 dwords: fully bank-spread, 52.8KB -> 3 blocks/CU
__global__ __launch_bounds__(256) void conv5_mfma(
    const unsigned short* __restrict__ xh,   // [B][H][W][64] bf16
    const unsigned short* __restrict__ wb,   // [25][8][16][8] bf16
    const float* __restrict__ bias,
    unsigned short* __restrict__ att)        // [B][9][H][W] bf16 (tanh)
{
    __shared__ unsigned short xs[20 * 20 * PADC];  // 52800 B

    int tid = threadIdx.x;
    int bx = blockIdx.x & 15;
    int by = (blockIdx.x >> 4) & 15;
    int b  = blockIdx.x >> 8;
    int h0 = by * 16, w0 = bx * 16;

    for (int q = tid; q < 400 * 8; q += 256) {
        int p = q & 7;
        int pix = q >> 3;
        int py = pix / 20, px = pix % 20;
        int gy = h0 + py - 2, gx = w0 + px - 2;
        short8 v = (short8)0;
        if (gy >= 0 && gy < H_ && gx >= 0 && gx < W_)
            v = *(const short8*)(xh + ((size_t)((b * 256 + gy) * 256 + gx) * 64 + p * 8));
        *(short8*)(&xs[pix * PADC + p * 8]) = v;
    }
    __syncthreads();

    int lane = tid & 63;
    int wid  = tid >> 6;
    int m16  = lane & 15;
    int lq   = lane >> 4;

    float4_ acc[4];
    float bj = (m16 < KK) ? bias[m16] : 0.f;
    #pragma unroll
    for (int r = 0; r < 4; ++r) acc[r] = (float4_){bj, bj, bj, bj};

    #pragma unroll
    for (int dj = 0; dj < 5; ++dj) {
        short8 bfr[5][2];
        #pragma unroll
        for (int di = 0; di < 5; ++di) {
            int tap = di * 5 + dj;
            bfr[di][0] = *(const short8*)(wb + (((tap * 8 + lq) * 16 + m16) * 8));
            bfr[di][1] = *(const short8*)(wb + (((tap * 8 + 4 + lq) * 16 + m16) * 8));
        }
        int px = m16 + dj;
        #pragma unroll
        for (int s = 0; s < 8; ++s) {
            const unsigned short* base = &xs[((wid * 4 + s) * 20 + px) * PADC + lq * 8];
            short8 a0 = *(const short8*)(base);
            short8 a1 = *(const short8*)(base + 32);
            #pragma unroll
            for (int di = 0; di < 5; ++di) {
                int r = s - di;
                if (r < 0 || r > 3) continue;
                acc[r] = __builtin_amdgcn_mfma_f32_16x16x32_bf16(a0, bfr[di][0], acc[r], 0, 0, 0);
                acc[r] = __builtin_amdgcn_mfma_f32_16x16x32_bf16(a1, bfr[di][1], acc[r], 0, 0, 0);
            }
        }
    }

    if (m16 < KK) {
        #pragma unroll
        for (int r = 0; r < 4; ++r) {
            int py = h0 + wid * 4 + r;
            #pragma unroll
            for (int reg = 0; reg < 4; ++reg) {
                int px = w0 + lq * 4 + reg;
                att[((b * KK + m16) << 16) | (py << 8) | px] = f2bf(tanhf(acc[r][reg]));
            }
        }
    }
}

// ---------------- Kernel D: per-pixel 3x3 dynamic filter, tiled (L2-aligned with conv5) ----------------
// Writes attf (NCHW f32, output) and d = x - attf (NHWC bf16).
__global__ __launch_bounds__(256) void perpix_nhwc(
    const unsigned short* __restrict__ xh, const unsigned short* __restrict__ att,
    float* __restrict__ attf, unsigned short* __restrict__ dh)
{
    int tid = threadIdx.x;
    int bx = blockIdx.x & 15;
    int by = (blockIdx.x >> 4) & 15;
    int b  = blockIdx.x >> 8;
    int h0 = by * 16, w0 = bx * 16;
    int g = tid & 7;

    #pragma unroll
    for (int it = 0; it < 8; ++it) {
        int pl = it * 32 + (tid >> 3);     // 0..255 local pixel
        int py = pl >> 4, px = pl & 15;
        int h = h0 + py, w = w0 + px;
        int hw = (h << 8) | w;

        float a[KK];
        #pragma unroll
        for (int j = 0; j < KK; ++j)
            a[j] = bf2f(att[((b * KK + j) << 16) | hw]);

        float s[8] = {0, 0, 0, 0, 0, 0, 0, 0};
        float xc[8] = {0, 0, 0, 0, 0, 0, 0, 0};
        #pragma unroll
        for (int di = 0; di < 3; ++di) {
            int y = h + di - 1;
            #pragma unroll
            for (int dj = 0; dj < 3; ++dj) {
                int xq = w + dj - 1;
                if (y < 0 || y >= H_ || xq < 0 || xq >= W_) continue;
                short8 v = *(const short8*)(xh + ((size_t)((b << 16) | (y << 8) | xq) * 64 + g * 8));
                float aj = a[di * 3 + dj];
                #pragma unroll
                for (int i = 0; i < 8; ++i) {
                    float xv = bf2f(v[i]);
                    s[i] += xv * aj;
                    if (di == 1 && dj == 1) xc[i] = xv;
                }
            }
        }

        #pragma unroll
        for (int i = 0; i < 8; ++i)
            attf[((size_t)(b * C_ + g * 8 + i) << 16) | hw] = s[i];

        short8 dv;
        #pragma unroll
        for (int i = 0; i < 8; ++i) dv[i] = (short)f2bf(xc[i] - s[i]);
        *(short8*)(dh + ((size_t)((b << 16) | hw) * 64 + g * 8)) = dv;
    }
}

// ---------------- Kernel E: fused conv3(64->9, MFMA) + conv3(9->9) + tanh ----------------
// Output tile 14x14; r1 computed on 16x16 (origin -1) from 18x18 d-stage; r1 in LDS.
#define NT 19   // ceil(256/14)
__global__ __launch_bounds__(256) void conv3_fused(
    const unsigned short* __restrict__ dh,   // [B][H][W][64] bf16
    const unsigned short* __restrict__ wb3,  // [9][8][16][8] bf16
    const float* __restrict__ b1,
    const float* __restrict__ w2,            // [9][9][3][3] f32
    const float* __restrict__ b2,
    float* __restrict__ out)                 // [B][9][H][W] f32 (tanh)
{
    __shared__ unsigned short xs[18 * 18 * PADC];  // 42768 B
    __shared__ float r1s[256 * 9];                 // 9216 B  [pix16x16][cin]

    int tid = threadIdx.x;
    int t_  = blockIdx.x;
    int bx = t_ % NT;  t_ /= NT;
    int by = t_ % NT;  t_ /= NT;
    int b  = t_;
    int h0 = by * 14, w0 = bx * 14;   // output tile origin
    int hr = h0 - 1,  wr = w0 - 1;    // r1 16x16 tile origin
    int hd = h0 - 2,  wd = w0 - 2;    // d 18x18 stage origin

    for (int q = tid; q < 324 * 8; q += 256) {
        int p = q & 7;
        int pix = q >> 3;
        int py = pix / 18, px = pix % 18;
        int gy = hd + py, gx = wd + px;
        short8 v = (short8)0;
        if (gy >= 0 && gy < H_ && gx >= 0 && gx < W_)
            v = *(const short8*)(dh + ((size_t)((b * 256 + gy) * 256 + gx) * 64 + p * 8));
        *(short8*)(&xs[pix * PADC + p * 8]) = v;
    }
    __syncthreads();

    int lane = tid & 63;
    int wid  = tid >> 6;
    int m16  = lane & 15;
    int lq   = lane >> 4;

    float4_ acc[4];
    float bj = (m16 < KK) ? b1[m16] : 0.f;
    #pragma unroll
    for (int r = 0; r < 4; ++r) acc[r] = (float4_){bj, bj, bj, bj};

    #pragma unroll
    for (int dj = 0; dj < 3; ++dj) {
        short8 bfr[3][2];
        #pragma unroll
        for (int di = 0; di < 3; ++di) {
            int tap = di * 3 + dj;
            bfr[di][0] = *(const short8*)(wb3 + (((tap * 8 + lq) * 16 + m16) * 8));
            bfr[di][1] = *(const short8*)(wb3 + (((tap * 8 + 4 + lq) * 16 + m16) * 8));
        }
        int px = m16 + dj;
        #pragma unroll
        for (int s = 0; s < 6; ++s) {
            const unsigned short* base = &xs[((wid * 4 + s) * 18 + px) * PADC + lq * 8];
            short8 a0 = *(const short8*)(base);
            short8 a1 = *(const short8*)(base + 32);
            #pragma unroll
            for (int di = 0; di < 3; ++di) {
                int r = s - di;
                if (r < 0 || r > 3) continue;
                acc[r] = __builtin_amdgcn_mfma_f32_16x16x32_bf16(a0, bfr[di][0], acc[r], 0, 0, 0);
                acc[r] = __builtin_amdgcn_mfma_f32_16x16x32_bf16(a1, bfr[di][1], acc[r], 0, 0, 0);
            }
        }
    }

    // r1 -> LDS, zero outside image (reference pad-0 semantics for r2)
    if (m16 < KK) {
        #pragma unroll
        for (int r = 0; r < 4; ++r) {
            int gy = hr + wid * 4 + r;
            #pragma unroll
            for (int reg = 0; reg < 4; ++reg) {
                int gx = wr + lq * 4 + reg;
                int pix = (wid * 4 + r) * 16 + lq * 4 + reg;
                float v = (gy >= 0 && gy < H_ && gx >= 0 && gx < W_) ? acc[r][reg] : 0.f;
                r1s[pix * 9 + m16] = v;
            }
        }
    }
    __syncthreads();

    // r2: 9->9 conv3x3 + bias + tanh over the 14x14 interior
    if (tid < 196) {
        int oy = tid / 14, ox = tid % 14;
        int gy = h0 + oy, gx = w0 + ox;
        if (gy < H_ && gx < W_) {
            float acc2[KK];
            #pragma unroll
            for (int j = 0; j < KK; ++j) acc2[j] = b2[j];
            #pragma unroll
            for (int di = 0; di < 3; ++di) {
                #pragma unroll
                for (int dj = 0; dj < 3; ++dj) {
                    const float* rv = &r1s[((oy + di) * 16 + ox + dj) * 9];
                    #pragma unroll
                    for (int cin = 0; cin < KK; ++cin) {
                        float xv = rv[cin];
                        #pragma unroll
                        for (int j = 0; j < KK; ++j)
                            acc2[j] += xv * w2[((j * KK + cin) * 3 + di) * 3 + dj];
                    }
                }
            }
            #pragma unroll
            for (int j = 0; j < KK; ++j)
                out[((b * KK + j) << 16) | (gy << 8) | gx] = tanhf(acc2[j]);
        }
    }
}

extern "C" void kernel_launch(void* const* d_in, const int* in_sizes, int n_in,
                              void* d_out, int out_size, void* d_ws, size_t ws_size,
                              hipStream_t stream) {
    const float* feature = (const float*)d_in[0];
    const float* w_sharp = (const float*)d_in[1];
    const float* b_sharp = (const float*)d_in[2];
    const float* w_r1    = (const float*)d_in[3];
    const float* b_r1    = (const float*)d_in[4];
    const float* w_r2    = (const float*)d_in[5];
    const float* b_r2    = (const float*)d_in[6];

    float* out_reblur = (float*)d_out;                          // [4,9,256,256]
    float* out_attf   = out_reblur + (size_t)B_ * KK * H_ * W_; // [4,64,256,256]

    char* ws = (char*)d_ws;
    unsigned short* xh   = (unsigned short*)ws;                  // 33554432 B
    unsigned short* dh   = (unsigned short*)(ws + 33554432);     // 33554432 B
    unsigned short* wb   = (unsigned short*)(ws + 67108864);     // 51200 -> pad 65536
    unsigned short* wb3  = (unsigned short*)(ws + 67174400);     // 18432 -> pad 32768
    unsigned short* att  = (unsigned short*)(ws + 67207168);     // 4718592 B bf16

    nchw2nhwc<<<1024, 256, 0, stream>>>(feature, xh);
    wprep_all<<<136, 256, 0, stream>>>(w_sharp, w_r1, wb, wb3);
    conv5_mfma<<<1024, 256, 0, stream>>>(xh, wb, b_sharp, att);
    perpix_nhwc<<<1024, 256, 0, stream>>>(xh, att, out_attf, dh);
    conv3_fused<<<NT * NT * B_, 256, 0, stream>>>(dh, wb3, b_r1, w_r2, b_r2, out_reblur);
}

// Round 6
// 168.242 us; speedup vs baseline: 1.0913x; 1.0913x over previous
//
#include <hip/hip_runtime.h>

#define B_ 4
#define C_ 64
#define H_ 256
#define W_ 256
#define KK 9

typedef __attribute__((ext_vector_type(8))) short short8;
typedef __attribute__((ext_vector_type(4))) float float4_;

static __device__ __forceinline__ unsigned short f2bf(float f) {
    unsigned int u = __builtin_bit_cast(unsigned int, f);
    unsigned int r = (u + 0x7fffu + ((u >> 16) & 1u)) >> 16;  // RNE
    return (unsigned short)r;
}
static __device__ __forceinline__ float bf2f(short s) {
    return __builtin_bit_cast(float, (unsigned int)((unsigned short)s) << 16);
}

// ---------------- Kernel A: NCHW fp32 -> NHWC bf16 (LDS transpose) ----------------
__global__ __launch_bounds__(256) void nchw2nhwc(
    const float* __restrict__ x, unsigned short* __restrict__ xh)
{
    __shared__ unsigned short t[256 * 66];
    int row = blockIdx.x;                   // b*256 + h
    int b = row >> 8;
    const float* src = x + ((size_t)b * 64) * 65536 + (size_t)(row & 255) * 256;
    int tid = threadIdx.x;

    #pragma unroll 4
    for (int c = 0; c < 64; ++c)
        t[tid * 66 + c] = f2bf(src[(size_t)c * 65536 + tid]);
    __syncthreads();

    unsigned short* dst = xh + (size_t)row * 256 * 64;
    #pragma unroll
    for (int it = 0; it < 8; ++it) {
        int idx = it * 256 + tid;
        int pix = idx >> 3, g = idx & 7;
        short8 v = *(const short8*)(&t[pix * 66 + g * 8]);
        *(short8*)(dst + (size_t)pix * 64 + g * 8) = v;
    }
}

// ---------------- Kernel B: merged weight transforms ----------------
__global__ __launch_bounds__(256) void wprep_all(
    const float* __restrict__ w5, const float* __restrict__ w3,
    unsigned short* __restrict__ wb, unsigned short* __restrict__ wb3)
{
    int i = blockIdx.x * 256 + threadIdx.x;   // 25600 + 9216 = 34816
    if (i < 25600) {
        int tap = i >> 10;
        int q = (i >> 7) & 7;
        int n = (i >> 3) & 15;
        int e = i & 7;
        int c = q * 8 + e;
        int di = tap / 5, dj = tap % 5;
        float v = (n < KK) ? w5[((n * C_ + c) * 5 + di) * 5 + dj] : 0.f;
        wb[i] = f2bf(v);
    } else if (i < 34816) {
        int k = i - 25600;
        int tap = k >> 10;
        int q = (k >> 7) & 7;
        int n = (k >> 3) & 15;
        int e = k & 7;
        int c = q * 8 + e;
        int di = tap / 3, dj = tap % 3;
        float v = (n < KK) ? w3[((n * C_ + c) * 3 + di) * 3 + dj] : 0.f;
        wb3[k] = f2bf(v);
    }
}

// ---------------- Kernel C: conv5 + tanh via bf16 MFMA (att out bf16) ----------------
#define PADC 66   // stride 33 dwords, 52.8KB -> 3 blocks/CU
__global__ __launch_bounds__(256) void conv5_mfma(
    const unsigned short* __restrict__ xh,   // [B][H][W][64] bf16
    const unsigned short* __restrict__ wb,   // [25][8][16][8] bf16
    const float* __restrict__ bias,
    unsigned short* __restrict__ att)        // [B][9][H][W] bf16 (tanh)
{
    __shared__ unsigned short xs[20 * 20 * PADC];  // 52800 B

    int tid = threadIdx.x;
    int bx = blockIdx.x & 15;
    int by = (blockIdx.x >> 4) & 15;
    int b  = blockIdx.x >> 8;
    int h0 = by * 16, w0 = bx * 16;

    for (int q = tid; q < 400 * 8; q += 256) {
        int p = q & 7;
        int pix = q >> 3;
        int py = pix / 20, px = pix % 20;
        int gy = h0 + py - 2, gx = w0 + px - 2;
        short8 v = (short8)0;
        if (gy >= 0 && gy < H_ && gx >= 0 && gx < W_)
            v = *(const short8*)(xh + ((size_t)((b * 256 + gy) * 256 + gx) * 64 + p * 8));
        *(short8*)(&xs[pix * PADC + p * 8]) = v;
    }
    __syncthreads();

    int lane = tid & 63;
    int wid  = tid >> 6;
    int m16  = lane & 15;
    int lq   = lane >> 4;

    float4_ acc[4];
    float bj = (m16 < KK) ? bias[m16] : 0.f;
    #pragma unroll
    for (int r = 0; r < 4; ++r) acc[r] = (float4_){bj, bj, bj, bj};

    #pragma unroll
    for (int dj = 0; dj < 5; ++dj) {
        short8 bfr[5][2];
        #pragma unroll
        for (int di = 0; di < 5; ++di) {
            int tap = di * 5 + dj;
            bfr[di][0] = *(const short8*)(wb + (((tap * 8 + lq) * 16 + m16) * 8));
            bfr[di][1] = *(const short8*)(wb + (((tap * 8 + 4 + lq) * 16 + m16) * 8));
        }
        int px = m16 + dj;
        #pragma unroll
        for (int s = 0; s < 8; ++s) {
            const unsigned short* base = &xs[((wid * 4 + s) * 20 + px) * PADC + lq * 8];
            short8 a0 = *(const short8*)(base);
            short8 a1 = *(const short8*)(base + 32);
            #pragma unroll
            for (int di = 0; di < 5; ++di) {
                int r = s - di;
                if (r < 0 || r > 3) continue;
                acc[r] = __builtin_amdgcn_mfma_f32_16x16x32_bf16(a0, bfr[di][0], acc[r], 0, 0, 0);
                acc[r] = __builtin_amdgcn_mfma_f32_16x16x32_bf16(a1, bfr[di][1], acc[r], 0, 0, 0);
            }
        }
    }

    if (m16 < KK) {
        #pragma unroll
        for (int r = 0; r < 4; ++r) {
            int py = h0 + wid * 4 + r;
            #pragma unroll
            for (int reg = 0; reg < 4; ++reg) {
                int px = w0 + lq * 4 + reg;
                att[((b * KK + m16) << 16) | (py << 8) | px] = f2bf(tanhf(acc[r][reg]));
            }
        }
    }
}

// ---------------- Kernel D: per-pixel 3x3 dynamic filter (flat grid, proven) ----------------
// Writes attf (NCHW f32, output) and d = x - attf (NHWC bf16).
__global__ __launch_bounds__(256) void perpix_nhwc(
    const unsigned short* __restrict__ xh, const unsigned short* __restrict__ att,
    float* __restrict__ attf, unsigned short* __restrict__ dh)
{
    int t = blockIdx.x * 256 + threadIdx.x;   // 2097152
    int g = t & 7;
    int pix = t >> 3;
    int b = pix >> 16;
    int hw = pix & 65535;
    int h = hw >> 8, w = hw & 255;

    float a[KK];
    #pragma unroll
    for (int j = 0; j < KK; ++j)
        a[j] = bf2f(att[((b * KK + j) << 16) | hw]);

    float s[8] = {0, 0, 0, 0, 0, 0, 0, 0};
    float xc[8] = {0, 0, 0, 0, 0, 0, 0, 0};
    #pragma unroll
    for (int di = 0; di < 3; ++di) {
        int y = h + di - 1;
        #pragma unroll
        for (int dj = 0; dj < 3; ++dj) {
            int xq = w + dj - 1;
            if (y < 0 || y >= H_ || xq < 0 || xq >= W_) continue;
            short8 v = *(const short8*)(xh + ((size_t)((b << 16) | (y << 8) | xq) * 64 + g * 8));
            float aj = a[di * 3 + dj];
            #pragma unroll
            for (int i = 0; i < 8; ++i) {
                float xv = bf2f(v[i]);
                s[i] += xv * aj;
                if (di == 1 && dj == 1) xc[i] = xv;
            }
        }
    }

    #pragma unroll
    for (int i = 0; i < 8; ++i)
        attf[((size_t)(b * C_ + g * 8 + i) << 16) | hw] = s[i];

    short8 dv;
    #pragma unroll
    for (int i = 0; i < 8; ++i) dv[i] = (short)f2bf(xc[i] - s[i]);
    *(short8*)(dh + (size_t)pix * 64 + g * 8) = dv;
}

// ---------------- Kernel E: conv3 (64 -> 9) on d via bf16 MFMA, r1 out bf16 ----------------
__global__ __launch_bounds__(256) void conv3_mfma(
    const unsigned short* __restrict__ dh,   // [B][H][W][64] bf16
    const unsigned short* __restrict__ wb3,  // [9][8][16][8] bf16
    const float* __restrict__ bias,
    unsigned short* __restrict__ r1h)        // [B][9][H][W] bf16
{
    __shared__ unsigned short xs[18 * 18 * PADC];  // 42768 B

    int tid = threadIdx.x;
    int bx = blockIdx.x & 15;
    int by = (blockIdx.x >> 4) & 15;
    int b  = blockIdx.x >> 8;
    int h0 = by * 16, w0 = bx * 16;

    for (int q = tid; q < 324 * 8; q += 256) {
        int p = q & 7;
        int pix = q >> 3;
        int py = pix / 18, px = pix % 18;
        int gy = h0 + py - 1, gx = w0 + px - 1;
        short8 v = (short8)0;
        if (gy >= 0 && gy < H_ && gx >= 0 && gx < W_)
            v = *(const short8*)(dh + ((size_t)((b * 256 + gy) * 256 + gx) * 64 + p * 8));
        *(short8*)(&xs[pix * PADC + p * 8]) = v;
    }
    __syncthreads();

    int lane = tid & 63;
    int wid  = tid >> 6;
    int m16  = lane & 15;
    int lq   = lane >> 4;

    float4_ acc[4];
    float bj = (m16 < KK) ? bias[m16] : 0.f;
    #pragma unroll
    for (int r = 0; r < 4; ++r) acc[r] = (float4_){bj, bj, bj, bj};

    #pragma unroll
    for (int dj = 0; dj < 3; ++dj) {
        short8 bfr[3][2];
        #pragma unroll
        for (int di = 0; di < 3; ++di) {
            int tap = di * 3 + dj;
            bfr[di][0] = *(const short8*)(wb3 + (((tap * 8 + lq) * 16 + m16) * 8));
            bfr[di][1] = *(const short8*)(wb3 + (((tap * 8 + 4 + lq) * 16 + m16) * 8));
        }
        int px = m16 + dj;
        #pragma unroll
        for (int s = 0; s < 6; ++s) {
            const unsigned short* base = &xs[((wid * 4 + s) * 18 + px) * PADC + lq * 8];
            short8 a0 = *(const short8*)(base);
            short8 a1 = *(const short8*)(base + 32);
            #pragma unroll
            for (int di = 0; di < 3; ++di) {
                int r = s - di;
                if (r < 0 || r > 3) continue;
                acc[r] = __builtin_amdgcn_mfma_f32_16x16x32_bf16(a0, bfr[di][0], acc[r], 0, 0, 0);
                acc[r] = __builtin_amdgcn_mfma_f32_16x16x32_bf16(a1, bfr[di][1], acc[r], 0, 0, 0);
            }
        }
    }

    if (m16 < KK) {
        #pragma unroll
        for (int r = 0; r < 4; ++r) {
            int py = h0 + wid * 4 + r;
            #pragma unroll
            for (int reg = 0; reg < 4; ++reg) {
                int px = w0 + lq * 4 + reg;
                r1h[((b * KK + m16) << 16) | (py << 8) | px] = f2bf(acc[r][reg]);
            }
        }
    }
}

// ---------------- Kernel F: 3x3 conv (9 -> 9) + tanh, bf16 in ----------------
__global__ __launch_bounds__(256) void conv3_tanh9(
    const unsigned short* __restrict__ r1h, const float* __restrict__ w,
    const float* __restrict__ bias, float* __restrict__ out)
{
    const int TW = 32, TH = 8, PW = 34, PH = 10;
    __shared__ float lds[KK][PH][PW];

    int tid = threadIdx.x;
    int tx = tid & 31, ty = tid >> 5;
    int bw = blockIdx.x & 7;
    int bh = (blockIdx.x >> 3) & 31;
    int b  = blockIdx.x >> 8;
    int h0 = bh * TH, w0 = bw * TW;

    for (int idx = tid; idx < KK * PH * PW; idx += 256) {
        int px = idx % PW;
        int py = (idx / PW) % PH;
        int ch = idx / (PW * PH);
        int gy = h0 + py - 1, gx = w0 + px - 1;
        float v = 0.f;
        if (gy >= 0 && gy < H_ && gx >= 0 && gx < W_)
            v = bf2f(r1h[((b * KK + ch) << 16) | (gy << 8) | gx]);
        lds[ch][py][px] = v;
    }
    __syncthreads();

    float acc[KK];
    #pragma unroll
    for (int j = 0; j < KK; ++j) acc[j] = bias[j];

    for (int cin = 0; cin < KK; ++cin) {
        #pragma unroll
        for (int di = 0; di < 3; ++di) {
            #pragma unroll
            for (int dj = 0; dj < 3; ++dj) {
                float xv = lds[cin][ty + di][tx + dj];
                #pragma unroll
                for (int j = 0; j < KK; ++j)
                    acc[j] += xv * w[((j * KK + cin) * 3 + di) * 3 + dj];
            }
        }
    }

    int h = h0 + ty, wq = w0 + tx;
    #pragma unroll
    for (int j = 0; j < KK; ++j)
        out[((b * KK + j) << 16) | (h << 8) | wq] = tanhf(acc[j]);
}

extern "C" void kernel_launch(void* const* d_in, const int* in_sizes, int n_in,
                              void* d_out, int out_size, void* d_ws, size_t ws_size,
                              hipStream_t stream) {
    const float* feature = (const float*)d_in[0];
    const float* w_sharp = (const float*)d_in[1];
    const float* b_sharp = (const float*)d_in[2];
    const float* w_r1    = (const float*)d_in[3];
    const float* b_r1    = (const float*)d_in[4];
    const float* w_r2    = (const float*)d_in[5];
    const float* b_r2    = (const float*)d_in[6];

    float* out_reblur = (float*)d_out;                          // [4,9,256,256]
    float* out_attf   = out_reblur + (size_t)B_ * KK * H_ * W_; // [4,64,256,256]

    char* ws = (char*)d_ws;
    unsigned short* xh   = (unsigned short*)ws;                  // 33554432 B
    unsigned short* dh   = (unsigned short*)(ws + 33554432);     // 33554432 B
    unsigned short* wb   = (unsigned short*)(ws + 67108864);     // 51200 -> pad 65536
    unsigned short* wb3  = (unsigned short*)(ws + 67174400);     // 18432 -> pad 32768
    unsigned short* att  = (unsigned short*)(ws + 67207168);     // 4718592 B bf16
    unsigned short* r1h  = att;  // alias: att fully consumed by perpix before conv3_mfma writes r1

    nchw2nhwc<<<1024, 256, 0, stream>>>(feature, xh);
    wprep_all<<<136, 256, 0, stream>>>(w_sharp, w_r1, wb, wb3);
    conv5_mfma<<<1024, 256, 0, stream>>>(xh, wb, b_sharp, att);
    perpix_nhwc<<<8192, 256, 0, stream>>>(xh, att, out_attf, dh);
    conv3_mfma<<<1024, 256, 0, stream>>>(dh, wb3, b_r1, r1h);
    conv3_tanh9<<<1024, 256, 0, stream>>>(r1h, w_r2, b_r2, out_reblur);
}

// Round 7
// 123.576 us; speedup vs baseline: 1.4857x; 1.3614x over previous
//
#include <hip/hip_runtime.h>

#define B_ 4
#define C_ 64
#define H_ 256
#define W_ 256
#define KK 9

typedef __attribute__((ext_vector_type(8))) short short8;
typedef __attribute__((ext_vector_type(4))) float float4_;

static __device__ __forceinline__ unsigned short f2bf(float f) {
    unsigned int u = __builtin_bit_cast(unsigned int, f);
    unsigned int r = (u + 0x7fffu + ((u >> 16) & 1u)) >> 16;  // RNE
    return (unsigned short)r;
}
static __device__ __forceinline__ float bf2f(short s) {
    return __builtin_bit_cast(float, (unsigned int)((unsigned short)s) << 16);
}

// ---------------- Kernel A: NCHW fp32 -> NHWC bf16 (LDS transpose) ----------------
__global__ __launch_bounds__(256) void nchw2nhwc(
    const float* __restrict__ x, unsigned short* __restrict__ xh)
{
    __shared__ unsigned short t[256 * 66];
    int row = blockIdx.x;                   // b*256 + h
    int b = row >> 8;
    const float* src = x + ((size_t)b * 64) * 65536 + (size_t)(row & 255) * 256;
    int tid = threadIdx.x;

    #pragma unroll 4
    for (int c = 0; c < 64; ++c)
        t[tid * 66 + c] = f2bf(src[(size_t)c * 65536 + tid]);
    __syncthreads();

    unsigned short* dst = xh + (size_t)row * 256 * 64;
    #pragma unroll
    for (int it = 0; it < 8; ++it) {
        int idx = it * 256 + tid;
        int pix = idx >> 3, g = idx & 7;
        short8 v = *(const short8*)(&t[pix * 66 + g * 8]);
        *(short8*)(dst + (size_t)pix * 64 + g * 8) = v;
    }
}

// ---------------- Kernel B: merged weight transforms ----------------
__global__ __launch_bounds__(256) void wprep_all(
    const float* __restrict__ w5, const float* __restrict__ w3,
    unsigned short* __restrict__ wb, unsigned short* __restrict__ wb3)
{
    int i = blockIdx.x * 256 + threadIdx.x;   // 25600 + 9216 = 34816
    if (i < 25600) {
        int tap = i >> 10;
        int q = (i >> 7) & 7;
        int n = (i >> 3) & 15;
        int e = i & 7;
        int c = q * 8 + e;
        int di = tap / 5, dj = tap % 5;
        float v = (n < KK) ? w5[((n * C_ + c) * 5 + di) * 5 + dj] : 0.f;
        wb[i] = f2bf(v);
    } else if (i < 34816) {
        int k = i - 25600;
        int tap = k >> 10;
        int q = (k >> 7) & 7;
        int n = (k >> 3) & 15;
        int e = k & 7;
        int c = q * 8 + e;
        int di = tap / 3, dj = tap % 3;
        float v = (n < KK) ? w3[((n * C_ + c) * 3 + di) * 3 + dj] : 0.f;
        wb3[k] = f2bf(v);
    }
}

// ---------------- Kernel C: conv5 + tanh via bf16 MFMA ----------------
// LDS: [pix][chunk] with chunk XOR-swizzle: chunk p of pixel pix stored at
// (p ^ (pix&7))*8 shorts. 16B-aligned (ds_*_b128) AND conflict-free.
__global__ __launch_bounds__(256) void conv5_mfma(
    const unsigned short* __restrict__ xh,   // [B][H][W][64] bf16
    const unsigned short* __restrict__ wb,   // [25][8][16][8] bf16
    const float* __restrict__ bias,
    unsigned short* __restrict__ att)        // [B][9][H][W] bf16 (tanh)
{
    __shared__ unsigned short xs[20 * 20 * 64];  // 51200 B -> 3 blocks/CU

    int tid = threadIdx.x;
    int bx = blockIdx.x & 15;
    int by = (blockIdx.x >> 4) & 15;
    int b  = blockIdx.x >> 8;
    int h0 = by * 16, w0 = bx * 16;

    for (int q = tid; q < 400 * 8; q += 256) {
        int p = q & 7;
        int pix = q >> 3;
        int py = pix / 20, px = pix % 20;
        int gy = h0 + py - 2, gx = w0 + px - 2;
        short8 v = (short8)0;
        if (gy >= 0 && gy < H_ && gx >= 0 && gx < W_)
            v = *(const short8*)(xh + ((size_t)((b * 256 + gy) * 256 + gx) * 64 + p * 8));
        *(short8*)(&xs[(pix << 6) + ((p ^ (pix & 7)) << 3)]) = v;
    }
    __syncthreads();

    int lane = tid & 63;
    int wid  = tid >> 6;
    int m16  = lane & 15;
    int lq   = lane >> 4;

    float4_ acc[4];
    float bj = (m16 < KK) ? bias[m16] : 0.f;
    #pragma unroll
    for (int r = 0; r < 4; ++r) acc[r] = (float4_){bj, bj, bj, bj};

    #pragma unroll
    for (int dj = 0; dj < 5; ++dj) {
        short8 bfr[5][2];
        #pragma unroll
        for (int di = 0; di < 5; ++di) {
            int tap = di * 5 + dj;
            bfr[di][0] = *(const short8*)(wb + (((tap * 8 + lq) * 16 + m16) * 8));
            bfr[di][1] = *(const short8*)(wb + (((tap * 8 + 4 + lq) * 16 + m16) * 8));
        }
        int px = m16 + dj;
        #pragma unroll
        for (int s = 0; s < 8; ++s) {
            int pix = (wid * 4 + s) * 20 + px;
            int c0 = lq ^ (pix & 7);
            short8 a0 = *(const short8*)(&xs[(pix << 6) + (c0 << 3)]);
            short8 a1 = *(const short8*)(&xs[(pix << 6) + ((c0 ^ 4) << 3)]);
            #pragma unroll
            for (int di = 0; di < 5; ++di) {
                int r = s - di;
                if (r < 0 || r > 3) continue;
                acc[r] = __builtin_amdgcn_mfma_f32_16x16x32_bf16(a0, bfr[di][0], acc[r], 0, 0, 0);
                acc[r] = __builtin_amdgcn_mfma_f32_16x16x32_bf16(a1, bfr[di][1], acc[r], 0, 0, 0);
            }
        }
    }

    if (m16 < KK) {
        #pragma unroll
        for (int r = 0; r < 4; ++r) {
            int py = h0 + wid * 4 + r;
            #pragma unroll
            for (int reg = 0; reg < 4; ++reg) {
                int px = w0 + lq * 4 + reg;
                att[((b * KK + m16) << 16) | (py << 8) | px] = f2bf(tanhf(acc[r][reg]));
            }
        }
    }
}

// ---------------- Kernel D: per-pixel 3x3 dynamic filter (flat grid) ----------------
// Writes attf (NCHW f32, output) and d = x - attf (NHWC bf16).
__global__ __launch_bounds__(256) void perpix_nhwc(
    const unsigned short* __restrict__ xh, const unsigned short* __restrict__ att,
    float* __restrict__ attf, unsigned short* __restrict__ dh)
{
    int t = blockIdx.x * 256 + threadIdx.x;   // 2097152
    int g = t & 7;
    int pix = t >> 3;
    int b = pix >> 16;
    int hw = pix & 65535;
    int h = hw >> 8, w = hw & 255;

    float a[KK];
    #pragma unroll
    for (int j = 0; j < KK; ++j)
        a[j] = bf2f(att[((b * KK + j) << 16) | hw]);

    float s[8] = {0, 0, 0, 0, 0, 0, 0, 0};
    float xc[8] = {0, 0, 0, 0, 0, 0, 0, 0};
    #pragma unroll
    for (int di = 0; di < 3; ++di) {
        int y = h + di - 1;
        #pragma unroll
        for (int dj = 0; dj < 3; ++dj) {
            int xq = w + dj - 1;
            if (y < 0 || y >= H_ || xq < 0 || xq >= W_) continue;
            short8 v = *(const short8*)(xh + ((size_t)((b << 16) | (y << 8) | xq) * 64 + g * 8));
            float aj = a[di * 3 + dj];
            #pragma unroll
            for (int i = 0; i < 8; ++i) {
                float xv = bf2f(v[i]);
                s[i] += xv * aj;
                if (di == 1 && dj == 1) xc[i] = xv;
            }
        }
    }

    #pragma unroll
    for (int i = 0; i < 8; ++i)
        attf[((size_t)(b * C_ + g * 8 + i) << 16) | hw] = s[i];

    short8 dv;
    #pragma unroll
    for (int i = 0; i < 8; ++i) dv[i] = (short)f2bf(xc[i] - s[i]);
    *(short8*)(dh + (size_t)pix * 64 + g * 8) = dv;
}

// ---------------- Kernel E: conv3 (64 -> 9) on d via bf16 MFMA, r1 out bf16 ----------------
__global__ __launch_bounds__(256) void conv3_mfma(
    const unsigned short* __restrict__ dh,   // [B][H][W][64] bf16
    const unsigned short* __restrict__ wb3,  // [9][8][16][8] bf16
    const float* __restrict__ bias,
    unsigned short* __restrict__ r1h)        // [B][9][H][W] bf16
{
    __shared__ unsigned short xs[18 * 18 * 64];  // 41472 B

    int tid = threadIdx.x;
    int bx = blockIdx.x & 15;
    int by = (blockIdx.x >> 4) & 15;
    int b  = blockIdx.x >> 8;
    int h0 = by * 16, w0 = bx * 16;

    for (int q = tid; q < 324 * 8; q += 256) {
        int p = q & 7;
        int pix = q >> 3;
        int py = pix / 18, px = pix % 18;
        int gy = h0 + py - 1, gx = w0 + px - 1;
        short8 v = (short8)0;
        if (gy >= 0 && gy < H_ && gx >= 0 && gx < W_)
            v = *(const short8*)(dh + ((size_t)((b * 256 + gy) * 256 + gx) * 64 + p * 8));
        *(short8*)(&xs[(pix << 6) + ((p ^ (pix & 7)) << 3)]) = v;
    }
    __syncthreads();

    int lane = tid & 63;
    int wid  = tid >> 6;
    int m16  = lane & 15;
    int lq   = lane >> 4;

    float4_ acc[4];
    float bj = (m16 < KK) ? bias[m16] : 0.f;
    #pragma unroll
    for (int r = 0; r < 4; ++r) acc[r] = (float4_){bj, bj, bj, bj};

    #pragma unroll
    for (int dj = 0; dj < 3; ++dj) {
        short8 bfr[3][2];
        #pragma unroll
        for (int di = 0; di < 3; ++di) {
            int tap = di * 3 + dj;
            bfr[di][0] = *(const short8*)(wb3 + (((tap * 8 + lq) * 16 + m16) * 8));
            bfr[di][1] = *(const short8*)(wb3 + (((tap * 8 + 4 + lq) * 16 + m16) * 8));
        }
        int px = m16 + dj;
        #pragma unroll
        for (int s = 0; s < 6; ++s) {
            int pix = (wid * 4 + s) * 18 + px;
            int c0 = lq ^ (pix & 7);
            short8 a0 = *(const short8*)(&xs[(pix << 6) + (c0 << 3)]);
            short8 a1 = *(const short8*)(&xs[(pix << 6) + ((c0 ^ 4) << 3)]);
            #pragma unroll
            for (int di = 0; di < 3; ++di) {
                int r = s - di;
                if (r < 0 || r > 3) continue;
                acc[r] = __builtin_amdgcn_mfma_f32_16x16x32_bf16(a0, bfr[di][0], acc[r], 0, 0, 0);
                acc[r] = __builtin_amdgcn_mfma_f32_16x16x32_bf16(a1, bfr[di][1], acc[r], 0, 0, 0);
            }
        }
    }

    if (m16 < KK) {
        #pragma unroll
        for (int r = 0; r < 4; ++r) {
            int py = h0 + wid * 4 + r;
            #pragma unroll
            for (int reg = 0; reg < 4; ++reg) {
                int px = w0 + lq * 4 + reg;
                r1h[((b * KK + m16) << 16) | (py << 8) | px] = f2bf(acc[r][reg]);
            }
        }
    }
}

// ---------------- Kernel F: 3x3 conv (9 -> 9) + tanh, bf16 in ----------------
__global__ __launch_bounds__(256) void conv3_tanh9(
    const unsigned short* __restrict__ r1h, const float* __restrict__ w,
    const float* __restrict__ bias, float* __restrict__ out)
{
    const int TW = 32, TH = 8, PW = 34, PH = 10;
    __shared__ float lds[KK][PH][PW];

    int tid = threadIdx.x;
    int tx = tid & 31, ty = tid >> 5;
    int bw = blockIdx.x & 7;
    int bh = (blockIdx.x >> 3) & 31;
    int b  = blockIdx.x >> 8;
    int h0 = bh * TH, w0 = bw * TW;

    for (int idx = tid; idx < KK * PH * PW; idx += 256) {
        int px = idx % PW;
        int py = (idx / PW) % PH;
        int ch = idx / (PW * PH);
        int gy = h0 + py - 1, gx = w0 + px - 1;
        float v = 0.f;
        if (gy >= 0 && gy < H_ && gx >= 0 && gx < W_)
            v = bf2f(r1h[((b * KK + ch) << 16) | (gy << 8) | gx]);
        lds[ch][py][px] = v;
    }
    __syncthreads();

    float acc[KK];
    #pragma unroll
    for (int j = 0; j < KK; ++j) acc[j] = bias[j];

    for (int cin = 0; cin < KK; ++cin) {
        #pragma unroll
        for (int di = 0; di < 3; ++di) {
            #pragma unroll
            for (int dj = 0; dj < 3; ++dj) {
                float xv = lds[cin][ty + di][tx + dj];
                #pragma unroll
                for (int j = 0; j < KK; ++j)
                    acc[j] += xv * w[((j * KK + cin) * 3 + di) * 3 + dj];
            }
        }
    }

    int h = h0 + ty, wq = w0 + tx;
    #pragma unroll
    for (int j = 0; j < KK; ++j)
        out[((b * KK + j) << 16) | (h << 8) | wq] = tanhf(acc[j]);
}

extern "C" void kernel_launch(void* const* d_in, const int* in_sizes, int n_in,
                              void* d_out, int out_size, void* d_ws, size_t ws_size,
                              hipStream_t stream) {
    const float* feature = (const float*)d_in[0];
    const float* w_sharp = (const float*)d_in[1];
    const float* b_sharp = (const float*)d_in[2];
    const float* w_r1    = (const float*)d_in[3];
    const float* b_r1    = (const float*)d_in[4];
    const float* w_r2    = (const float*)d_in[5];
    const float* b_r2    = (const float*)d_in[6];

    float* out_reblur = (float*)d_out;                          // [4,9,256,256]
    float* out_attf   = out_reblur + (size_t)B_ * KK * H_ * W_; // [4,64,256,256]

    char* ws = (char*)d_ws;
    unsigned short* xh   = (unsigned short*)ws;                  // 33554432 B
    unsigned short* dh   = (unsigned short*)(ws + 33554432);     // 33554432 B
    unsigned short* wb   = (unsigned short*)(ws + 67108864);     // 51200 -> pad 65536
    unsigned short* wb3  = (unsigned short*)(ws + 67174400);     // 18432 -> pad 32768
    unsigned short* att  = (unsigned short*)(ws + 67207168);     // 4718592 B bf16
    unsigned short* r1h  = att;  // alias: att fully consumed by perpix before conv3_mfma writes r1

    nchw2nhwc<<<1024, 256, 0, stream>>>(feature, xh);
    wprep_all<<<136, 256, 0, stream>>>(w_sharp, w_r1, wb, wb3);
    conv5_mfma<<<1024, 256, 0, stream>>>(xh, wb, b_sharp, att);
    perpix_nhwc<<<8192, 256, 0, stream>>>(xh, att, out_attf, dh);
    conv3_mfma<<<1024, 256, 0, stream>>>(dh, wb3, b_r1, r1h);
    conv3_tanh9<<<1024, 256, 0, stream>>>(r1h, w_r2, b_r2, out_reblur);
}

// Round 8
// 117.969 us; speedup vs baseline: 1.5563x; 1.0475x over previous
//
#include <hip/hip_runtime.h>

#define B_ 4
#define C_ 64
#define H_ 256
#define W_ 256
#define KK 9

typedef __attribute__((ext_vector_type(8))) short short8;
typedef __attribute__((ext_vector_type(4))) float float4_;

static __device__ __forceinline__ unsigned short f2bf(float f) {
    unsigned int u = __builtin_bit_cast(unsigned int, f);
    unsigned int r = (u + 0x7fffu + ((u >> 16) & 1u)) >> 16;  // RNE
    return (unsigned short)r;
}
static __device__ __forceinline__ float bf2f(short s) {
    return __builtin_bit_cast(float, (unsigned int)((unsigned short)s) << 16);
}
// async global->LDS, 16B per lane; LDS dest is WAVE-UNIFORM base + lane*16 (HW adds it)
static __device__ __forceinline__ void gld16(const unsigned short* gp, unsigned short* lbase) {
    __builtin_amdgcn_global_load_lds(
        (const __attribute__((address_space(1))) unsigned int*)gp,
        (__attribute__((address_space(3))) unsigned int*)lbase, 16, 0, 0);
}

// ---------------- Kernel A: NCHW fp32 -> NHWC bf16 (LDS transpose) ----------------
__global__ __launch_bounds__(256) void nchw2nhwc(
    const float* __restrict__ x, unsigned short* __restrict__ xh)
{
    __shared__ unsigned short t[256 * 66];
    int row = blockIdx.x;                   // b*256 + h
    int b = row >> 8;
    const float* src = x + ((size_t)b * 64) * 65536 + (size_t)(row & 255) * 256;
    int tid = threadIdx.x;

    #pragma unroll 4
    for (int c = 0; c < 64; ++c)
        t[tid * 66 + c] = f2bf(src[(size_t)c * 65536 + tid]);
    __syncthreads();

    unsigned short* dst = xh + (size_t)row * 256 * 64;
    #pragma unroll
    for (int it = 0; it < 8; ++it) {
        int idx = it * 256 + tid;
        int pix = idx >> 3, g = idx & 7;
        short8 v = *(const short8*)(&t[pix * 66 + g * 8]);
        *(short8*)(dst + (size_t)pix * 64 + g * 8) = v;
    }
}

// ---------------- Kernel B: merged weight transforms ----------------
__global__ __launch_bounds__(256) void wprep_all(
    const float* __restrict__ w5, const float* __restrict__ w3,
    unsigned short* __restrict__ wb, unsigned short* __restrict__ wb3)
{
    int i = blockIdx.x * 256 + threadIdx.x;   // 25600 + 9216 = 34816
    if (i < 25600) {
        int tap = i >> 10;
        int q = (i >> 7) & 7;
        int n = (i >> 3) & 15;
        int e = i & 7;
        int c = q * 8 + e;
        int di = tap / 5, dj = tap % 5;
        float v = (n < KK) ? w5[((n * C_ + c) * 5 + di) * 5 + dj] : 0.f;
        wb[i] = f2bf(v);
    } else if (i < 34816) {
        int k = i - 25600;
        int tap = k >> 10;
        int q = (k >> 7) & 7;
        int n = (k >> 3) & 15;
        int e = k & 7;
        int c = q * 8 + e;
        int di = tap / 3, dj = tap % 3;
        float v = (n < KK) ? w3[((n * C_ + c) * 3 + di) * 3 + dj] : 0.f;
        wb3[k] = f2bf(v);
    }
}

// Shared staging: x 20x20x64 into swizzled LDS. Interior blocks use global_load_lds
// with the swizzle applied to the GLOBAL source (linear LDS dest); boundary blocks
// use the VGPR path with zero fill. Swizzle invariant: slot s of pixel pix holds
// global chunk p = s ^ (pix & 7).
static __device__ __forceinline__ void stage20(
    const unsigned short* __restrict__ xh, unsigned short* xs,
    int b, int h0, int w0, bool interior, int tid)
{
    if (interior) {
        int lane = tid & 63, wid = tid >> 6;
        int p = (lane & 7) ^ ((lane >> 3) & 7);   // global chunk for this lane's slot
        int sub = lane >> 3;                      // pixel within 8-pixel window
        for (int it = wid; it < 50; it += 4) {
            int pix = it * 8 + sub;
            int py = pix / 20, px = pix % 20;
            int gy = h0 + py - 2, gx = w0 + px - 2;
            const unsigned short* g = xh + ((size_t)((b * 256 + gy) * 256 + gx) * 64 + p * 8);
            gld16(g, &xs[it * 512]);              // wave-uniform base; HW adds lane*16B
        }
    } else {
        for (int q = tid; q < 400 * 8; q += 256) {
            int p = q & 7;
            int pix = q >> 3;
            int py = pix / 20, px = pix % 20;
            int gy = h0 + py - 2, gx = w0 + px - 2;
            short8 v = (short8)0;
            if (gy >= 0 && gy < H_ && gx >= 0 && gx < W_)
                v = *(const short8*)(xh + ((size_t)((b * 256 + gy) * 256 + gx) * 64 + p * 8));
            *(short8*)(&xs[(pix << 6) + ((p ^ (pix & 7)) << 3)]) = v;
        }
    }
}

// ---------------- Kernel C: conv5 + tanh via bf16 MFMA ----------------
__global__ __launch_bounds__(256) void conv5_mfma(
    const unsigned short* __restrict__ xh,   // [B][H][W][64] bf16
    const unsigned short* __restrict__ wb,   // [25][8][16][8] bf16
    const float* __restrict__ bias,
    unsigned short* __restrict__ att)        // [B][9][H][W] bf16 (tanh)
{
    __shared__ unsigned short xs[20 * 20 * 64];  // 51200 B -> 3 blocks/CU

    int tid = threadIdx.x;
    int bx = blockIdx.x & 15;
    int by = (blockIdx.x >> 4) & 15;
    int b  = blockIdx.x >> 8;
    int h0 = by * 16, w0 = bx * 16;
    bool interior = (bx >= 1 && bx <= 14 && by >= 1 && by <= 14);

    stage20(xh, xs, b, h0, w0, interior, tid);
    __syncthreads();

    int lane = tid & 63;
    int wid  = tid >> 6;
    int m16  = lane & 15;
    int lq   = lane >> 4;

    float4_ acc[4];
    float bj = (m16 < KK) ? bias[m16] : 0.f;
    #pragma unroll
    for (int r = 0; r < 4; ++r) acc[r] = (float4_){bj, bj, bj, bj};

    #pragma unroll
    for (int dj = 0; dj < 5; ++dj) {
        short8 bfr[5][2];
        #pragma unroll
        for (int di = 0; di < 5; ++di) {
            int tap = di * 5 + dj;
            bfr[di][0] = *(const short8*)(wb + (((tap * 8 + lq) * 16 + m16) * 8));
            bfr[di][1] = *(const short8*)(wb + (((tap * 8 + 4 + lq) * 16 + m16) * 8));
        }
        int px = m16 + dj;
        #pragma unroll
        for (int s = 0; s < 8; ++s) {
            int pix = (wid * 4 + s) * 20 + px;
            int c0 = lq ^ (pix & 7);
            short8 a0 = *(const short8*)(&xs[(pix << 6) + (c0 << 3)]);
            short8 a1 = *(const short8*)(&xs[(pix << 6) + ((c0 ^ 4) << 3)]);
            #pragma unroll
            for (int di = 0; di < 5; ++di) {
                int r = s - di;
                if (r < 0 || r > 3) continue;
                acc[r] = __builtin_amdgcn_mfma_f32_16x16x32_bf16(a0, bfr[di][0], acc[r], 0, 0, 0);
                acc[r] = __builtin_amdgcn_mfma_f32_16x16x32_bf16(a1, bfr[di][1], acc[r], 0, 0, 0);
            }
        }
    }

    if (m16 < KK) {
        #pragma unroll
        for (int r = 0; r < 4; ++r) {
            int py = h0 + wid * 4 + r;
            #pragma unroll
            for (int reg = 0; reg < 4; ++reg) {
                int px = w0 + lq * 4 + reg;
                att[((b * KK + m16) << 16) | (py << 8) | px] = f2bf(tanhf(acc[r][reg]));
            }
        }
    }
}

// ---------------- Kernel D: FUSED per-pixel filter + conv3(64->9) MFMA ----------------
// Per 16x16 tile: stage x 20x20 -> compute d = x - perpix(x,att) on 18x18 into regs
// (writing attf for the interior 16x16) -> write d back into xs (18x18 layout) ->
// conv3 via MFMA -> r1 bf16 out. Eliminates the dh global round-trip entirely.
__global__ __launch_bounds__(256) void conv3_fused(
    const unsigned short* __restrict__ xh,   // [B][H][W][64] bf16
    const unsigned short* __restrict__ att,  // [B][9][H][W] bf16
    const unsigned short* __restrict__ wb3,  // [9][8][16][8] bf16
    const float* __restrict__ bias,
    float* __restrict__ attf,                // [B][64][H][W] f32 (output)
    unsigned short* __restrict__ r1h)        // [B][9][H][W] bf16
{
    __shared__ unsigned short xs[20 * 20 * 64];  // 51200 B -> 3 blocks/CU

    int tid = threadIdx.x;
    int bx = blockIdx.x & 15;
    int by = (blockIdx.x >> 4) & 15;
    int b  = blockIdx.x >> 8;
    int h0 = by * 16, w0 = bx * 16;
    bool interior = (bx >= 1 && bx <= 14 && by >= 1 && by <= 14);

    stage20(xh, xs, b, h0, w0, interior, tid);
    __syncthreads();

    // phase 2: per-pixel dynamic filter on the 18x18 region (origin h0-1,w0-1)
    short8 dreg[11];
    #pragma unroll
    for (int it = 0; it < 11; ++it) {
        dreg[it] = (short8)0;
        int idx = it * 256 + tid;               // (pix18, g) work item, 2592 total
        if (idx < 2592) {
            int g = idx & 7;
            int pix = idx >> 3;                 // 0..323
            int py = pix / 18, px = pix % 18;
            int gy = h0 + py - 1, gx = w0 + px - 1;
            if (gy >= 0 && gy < H_ && gx >= 0 && gx < W_) {
                int hw = (gy << 8) | gx;
                float a[KK];
                #pragma unroll
                for (int j = 0; j < KK; ++j)
                    a[j] = bf2f(att[((b * KK + j) << 16) | hw]);

                float s[8] = {0, 0, 0, 0, 0, 0, 0, 0};
                float xc[8];
                #pragma unroll
                for (int di = 0; di < 3; ++di) {
                    #pragma unroll
                    for (int dj = 0; dj < 3; ++dj) {
                        int pix20 = (py + di) * 20 + (px + dj);
                        int c = g ^ (pix20 & 7);
                        short8 v = *(const short8*)(&xs[(pix20 << 6) + (c << 3)]);
                        float aj = a[di * 3 + dj];
                        #pragma unroll
                        for (int i = 0; i < 8; ++i) {
                            float xv = bf2f(v[i]);
                            s[i] += xv * aj;
                            if (di == 1 && dj == 1) xc[i] = xv;
                        }
                    }
                }
                if (py >= 1 && py <= 16 && px >= 1 && px <= 16) {
                    #pragma unroll
                    for (int i = 0; i < 8; ++i)
                        attf[((b * C_ + g * 8 + i) << 16) | hw] = s[i];
                }
                short8 dv;
                #pragma unroll
                for (int i = 0; i < 8; ++i) dv[i] = (short)f2bf(xc[i] - s[i]);
                dreg[it] = dv;
            }
        }
    }
    __syncthreads();

    // phase 3: d back into xs as swizzled 18x18 layout
    #pragma unroll
    for (int it = 0; it < 11; ++it) {
        int idx = it * 256 + tid;
        if (idx < 2592) {
            int g = idx & 7;
            int pix = idx >> 3;
            *(short8*)(&xs[(pix << 6) + ((g ^ (pix & 7)) << 3)]) = dreg[it];
        }
    }
    __syncthreads();

    // phase 4: conv3 via MFMA on d (18x18, origin -1)
    int lane = tid & 63;
    int wid  = tid >> 6;
    int m16  = lane & 15;
    int lq   = lane >> 4;

    float4_ acc[4];
    float bj = (m16 < KK) ? bias[m16] : 0.f;
    #pragma unroll
    for (int r = 0; r < 4; ++r) acc[r] = (float4_){bj, bj, bj, bj};

    #pragma unroll
    for (int dj = 0; dj < 3; ++dj) {
        short8 bfr[3][2];
        #pragma unroll
        for (int di = 0; di < 3; ++di) {
            int tap = di * 3 + dj;
            bfr[di][0] = *(const short8*)(wb3 + (((tap * 8 + lq) * 16 + m16) * 8));
            bfr[di][1] = *(const short8*)(wb3 + (((tap * 8 + 4 + lq) * 16 + m16) * 8));
        }
        int px = m16 + dj;
        #pragma unroll
        for (int s = 0; s < 6; ++s) {
            int pix = (wid * 4 + s) * 18 + px;
            int c0 = lq ^ (pix & 7);
            short8 a0 = *(const short8*)(&xs[(pix << 6) + (c0 << 3)]);
            short8 a1 = *(const short8*)(&xs[(pix << 6) + ((c0 ^ 4) << 3)]);
            #pragma unroll
            for (int di = 0; di < 3; ++di) {
                int r = s - di;
                if (r < 0 || r > 3) continue;
                acc[r] = __builtin_amdgcn_mfma_f32_16x16x32_bf16(a0, bfr[di][0], acc[r], 0, 0, 0);
                acc[r] = __builtin_amdgcn_mfma_f32_16x16x32_bf16(a1, bfr[di][1], acc[r], 0, 0, 0);
            }
        }
    }

    if (m16 < KK) {
        #pragma unroll
        for (int r = 0; r < 4; ++r) {
            int py = h0 + wid * 4 + r;
            #pragma unroll
            for (int reg = 0; reg < 4; ++reg) {
                int px = w0 + lq * 4 + reg;
                r1h[((b * KK + m16) << 16) | (py << 8) | px] = f2bf(acc[r][reg]);
            }
        }
    }
}

// ---------------- Kernel F: 3x3 conv (9 -> 9) + tanh, bf16 in ----------------
__global__ __launch_bounds__(256) void conv3_tanh9(
    const unsigned short* __restrict__ r1h, const float* __restrict__ w,
    const float* __restrict__ bias, float* __restrict__ out)
{
    const int TW = 32, TH = 8, PW = 34, PH = 10;
    __shared__ float lds[KK][PH][PW];

    int tid = threadIdx.x;
    int tx = tid & 31, ty = tid >> 5;
    int bw = blockIdx.x & 7;
    int bh = (blockIdx.x >> 3) & 31;
    int b  = blockIdx.x >> 8;
    int h0 = bh * TH, w0 = bw * TW;

    for (int idx = tid; idx < KK * PH * PW; idx += 256) {
        int px = idx % PW;
        int py = (idx / PW) % PH;
        int ch = idx / (PW * PH);
        int gy = h0 + py - 1, gx = w0 + px - 1;
        float v = 0.f;
        if (gy >= 0 && gy < H_ && gx >= 0 && gx < W_)
            v = bf2f(r1h[((b * KK + ch) << 16) | (gy << 8) | gx]);
        lds[ch][py][px] = v;
    }
    __syncthreads();

    float acc[KK];
    #pragma unroll
    for (int j = 0; j < KK; ++j) acc[j] = bias[j];

    for (int cin = 0; cin < KK; ++cin) {
        #pragma unroll
        for (int di = 0; di < 3; ++di) {
            #pragma unroll
            for (int dj = 0; dj < 3; ++dj) {
                float xv = lds[cin][ty + di][tx + dj];
                #pragma unroll
                for (int j = 0; j < KK; ++j)
                    acc[j] += xv * w[((j * KK + cin) * 3 + di) * 3 + dj];
            }
        }
    }

    int h = h0 + ty, wq = w0 + tx;
    #pragma unroll
    for (int j = 0; j < KK; ++j)
        out[((b * KK + j) << 16) | (h << 8) | wq] = tanhf(acc[j]);
}

extern "C" void kernel_launch(void* const* d_in, const int* in_sizes, int n_in,
                              void* d_out, int out_size, void* d_ws, size_t ws_size,
                              hipStream_t stream) {
    const float* feature = (const float*)d_in[0];
    const float* w_sharp = (const float*)d_in[1];
    const float* b_sharp = (const float*)d_in[2];
    const float* w_r1    = (const float*)d_in[3];
    const float* b_r1    = (const float*)d_in[4];
    const float* w_r2    = (const float*)d_in[5];
    const float* b_r2    = (const float*)d_in[6];

    float* out_reblur = (float*)d_out;                          // [4,9,256,256]
    float* out_attf   = out_reblur + (size_t)B_ * KK * H_ * W_; // [4,64,256,256]

    char* ws = (char*)d_ws;
    unsigned short* xh   = (unsigned short*)ws;                  // 33554432 B
    unsigned short* wb   = (unsigned short*)(ws + 33554432);     // 51200 -> pad 65536
    unsigned short* wb3  = (unsigned short*)(ws + 33619968);     // 18432 -> pad 32768
    unsigned short* att  = (unsigned short*)(ws + 33652736);     // 4718592 B bf16
    unsigned short* r1h  = (unsigned short*)(ws + 38371328);     // 4718592 B bf16 (no alias: att halo still read while r1h written)

    nchw2nhwc<<<1024, 256, 0, stream>>>(feature, xh);
    wprep_all<<<136, 256, 0, stream>>>(w_sharp, w_r1, wb, wb3);
    conv5_mfma<<<1024, 256, 0, stream>>>(xh, wb, b_sharp, att);
    conv3_fused<<<1024, 256, 0, stream>>>(xh, att, wb3, b_r1, out_attf, r1h);
    conv3_tanh9<<<1024, 256, 0, stream>>>(r1h, w_r2, b_r2, out_reblur);
}